// Round 13
// baseline (523.331 us; speedup 1.0000x reference)
//
#include <hip/hip_runtime.h>
#include <hip/hip_bf16.h>

typedef __bf16 bf16x8 __attribute__((ext_vector_type(8)));
typedef float  f32x4  __attribute__((ext_vector_type(4)));

#define N_TOT   16384
#define K_TOT   16384
#define HALF_M  ((size_t)128 * 16384)
#define BN      256
#define BK      64
#define KSPLIT  4
#define KQ_LEN  (K_TOT / KSPLIT)      // 4096
#define NQSTEPS (KQ_LEN / BK)         // 64
#define OUT_ELEMS ((size_t)256 * 16384)

__device__ __forceinline__ unsigned short f2bf(float f) {
    __hip_bfloat16 h = __float2bfloat16(f);
    return __builtin_bit_cast(unsigned short, h);
}

// Swizzled byte offset: 128-B rows, 16-B granules, XOR row&7 into granule idx.
__device__ __forceinline__ int swz(int row, int g) {
    return row * 128 + (((g ^ (row & 7)) & 7) << 4);
}

// One-time T = concat(x0,x1) fp32 -> bf16 into workspace (linear row-major).
__global__ void cvtT_kernel(const float* __restrict__ x0,
                            const float* __restrict__ x1,
                            unsigned short* __restrict__ wsT) {
    size_t i = (size_t)blockIdx.x * blockDim.x + threadIdx.x;  // 0..524287
    size_t e = i * 8;
    const float* src = (e < HALF_M) ? (x0 + e) : (x1 + (e - HALF_M));
    float4 a = ((const float4*)src)[0];
    float4 b = ((const float4*)src)[1];
    union { unsigned short u[8]; uint4 v; } o;
    o.u[0] = f2bf(a.x); o.u[1] = f2bf(a.y); o.u[2] = f2bf(a.z); o.u[3] = f2bf(a.w);
    o.u[4] = f2bf(b.x); o.u[5] = f2bf(b.y); o.u[6] = f2bf(b.z); o.u[7] = f2bf(b.w);
    ((uint4*)wsT)[i] = o.v;
}

// out += p0 + p1 + p2 (fixed order -> deterministic)
__global__ void combine_kernel(float* __restrict__ out,
                               const float* __restrict__ p0,
                               const float* __restrict__ p1,
                               const float* __restrict__ p2) {
    const size_t n4 = OUT_ELEMS / 4;
    size_t i = (size_t)blockIdx.x * blockDim.x + threadIdx.x;
    for (; i < n4; i += (size_t)gridDim.x * blockDim.x) {
        float4 o = ((const float4*)out)[i];
        float4 a = ((const float4*)p0)[i];
        float4 b = ((const float4*)p1)[i];
        float4 c = ((const float4*)p2)[i];
        o.x += a.x + b.x + c.x;  o.y += a.y + b.y + c.y;
        o.z += a.z + b.z + c.z;  o.w += a.w + b.w + c.w;
        ((float4*)out)[i] = o;
    }
}

// ---- single-set prefetch, 512 threads ----
// A: thread covers 64 B of its wsT row (4 x uint4).
// W: thread covers 128 B fp32 of its W row (8 x f32x4) -> 64 B bf16.
#define ISSUE(k0) do {                                                        \
    const uint4* _p = (const uint4*)(arow_w + (k0));                          \
    aR0 = _p[0]; aR1 = _p[1]; aR2 = _p[2]; aR3 = _p[3];                       \
    const f32x4* _q = (const f32x4*)(brow + (k0));                            \
    wR0 = _q[0]; wR1 = _q[1]; wR2 = _q[2]; wR3 = _q[3];                       \
    wR4 = _q[4]; wR5 = _q[5]; wR6 = _q[6]; wR7 = _q[7];                       \
} while (0)

// cvt one 16-B granule (8 bf16) from two f32x4 and write it immediately
// (keeps only 4 transient VGPRs live).
#define CVT_WRITE(Bb, OFF, LO, HI) do {                                       \
    union { unsigned short u[8]; uint4 v; } _t;                               \
    _t.u[0]=f2bf((LO)[0]); _t.u[1]=f2bf((LO)[1]);                             \
    _t.u[2]=f2bf((LO)[2]); _t.u[3]=f2bf((LO)[3]);                             \
    _t.u[4]=f2bf((HI)[0]); _t.u[5]=f2bf((HI)[1]);                             \
    _t.u[6]=f2bf((HI)[2]); _t.u[7]=f2bf((HI)[3]);                             \
    *(uint4*)((Bb) + (OFF)) = _t.v;                                           \
} while (0)

#define STAGE(Ab, Bb) do {                                                    \
    *(uint4*)((Ab) + aw0) = aR0;                                              \
    *(uint4*)((Ab) + aw1) = aR1;                                              \
    *(uint4*)((Ab) + aw2) = aR2;                                              \
    *(uint4*)((Ab) + aw3) = aR3;                                              \
    CVT_WRITE(Bb, bw0, wR0, wR1);                                             \
    CVT_WRITE(Bb, bw1, wR2, wR3);                                             \
    CVT_WRITE(Bb, bw2, wR4, wR5);                                             \
    CVT_WRITE(Bb, bw3, wR6, wR7);                                             \
} while (0)

// One K-half: 8 A-frags held (32 VGPR), B-frags one at a time.
#define COMPUTE_HALF(Ab, Bb, AOFF, BOFF) do {                                 \
    bf16x8 _a0 = *(const bf16x8*)((Ab) + (AOFF) + 0*2048);                    \
    bf16x8 _a1 = *(const bf16x8*)((Ab) + (AOFF) + 1*2048);                    \
    bf16x8 _a2 = *(const bf16x8*)((Ab) + (AOFF) + 2*2048);                    \
    bf16x8 _a3 = *(const bf16x8*)((Ab) + (AOFF) + 3*2048);                    \
    bf16x8 _a4 = *(const bf16x8*)((Ab) + (AOFF) + 4*2048);                    \
    bf16x8 _a5 = *(const bf16x8*)((Ab) + (AOFF) + 5*2048);                    \
    bf16x8 _a6 = *(const bf16x8*)((Ab) + (AOFF) + 6*2048);                    \
    bf16x8 _a7 = *(const bf16x8*)((Ab) + (AOFF) + 7*2048);                    \
    bf16x8 _bv;                                                               \
    _bv = *(const bf16x8*)((Bb) + (BOFF) + 0*2048);                           \
    accA0 = __builtin_amdgcn_mfma_f32_16x16x32_bf16(_a0, _bv, accA0, 0,0,0);  \
    accA1 = __builtin_amdgcn_mfma_f32_16x16x32_bf16(_a1, _bv, accA1, 0,0,0);  \
    accA2 = __builtin_amdgcn_mfma_f32_16x16x32_bf16(_a2, _bv, accA2, 0,0,0);  \
    accA3 = __builtin_amdgcn_mfma_f32_16x16x32_bf16(_a3, _bv, accA3, 0,0,0);  \
    accA4 = __builtin_amdgcn_mfma_f32_16x16x32_bf16(_a4, _bv, accA4, 0,0,0);  \
    accA5 = __builtin_amdgcn_mfma_f32_16x16x32_bf16(_a5, _bv, accA5, 0,0,0);  \
    accA6 = __builtin_amdgcn_mfma_f32_16x16x32_bf16(_a6, _bv, accA6, 0,0,0);  \
    accA7 = __builtin_amdgcn_mfma_f32_16x16x32_bf16(_a7, _bv, accA7, 0,0,0);  \
    _bv = *(const bf16x8*)((Bb) + (BOFF) + 1*2048);                           \
    accB0 = __builtin_amdgcn_mfma_f32_16x16x32_bf16(_a0, _bv, accB0, 0,0,0);  \
    accB1 = __builtin_amdgcn_mfma_f32_16x16x32_bf16(_a1, _bv, accB1, 0,0,0);  \
    accB2 = __builtin_amdgcn_mfma_f32_16x16x32_bf16(_a2, _bv, accB2, 0,0,0);  \
    accB3 = __builtin_amdgcn_mfma_f32_16x16x32_bf16(_a3, _bv, accB3, 0,0,0);  \
    accB4 = __builtin_amdgcn_mfma_f32_16x16x32_bf16(_a4, _bv, accB4, 0,0,0);  \
    accB5 = __builtin_amdgcn_mfma_f32_16x16x32_bf16(_a5, _bv, accB5, 0,0,0);  \
    accB6 = __builtin_amdgcn_mfma_f32_16x16x32_bf16(_a6, _bv, accB6, 0,0,0);  \
    accB7 = __builtin_amdgcn_mfma_f32_16x16x32_bf16(_a7, _bv, accB7, 0,0,0);  \
    _bv = *(const bf16x8*)((Bb) + (BOFF) + 2*2048);                           \
    accC0 = __builtin_amdgcn_mfma_f32_16x16x32_bf16(_a0, _bv, accC0, 0,0,0);  \
    accC1 = __builtin_amdgcn_mfma_f32_16x16x32_bf16(_a1, _bv, accC1, 0,0,0);  \
    accC2 = __builtin_amdgcn_mfma_f32_16x16x32_bf16(_a2, _bv, accC2, 0,0,0);  \
    accC3 = __builtin_amdgcn_mfma_f32_16x16x32_bf16(_a3, _bv, accC3, 0,0,0);  \
    accC4 = __builtin_amdgcn_mfma_f32_16x16x32_bf16(_a4, _bv, accC4, 0,0,0);  \
    accC5 = __builtin_amdgcn_mfma_f32_16x16x32_bf16(_a5, _bv, accC5, 0,0,0);  \
    accC6 = __builtin_amdgcn_mfma_f32_16x16x32_bf16(_a6, _bv, accC6, 0,0,0);  \
    accC7 = __builtin_amdgcn_mfma_f32_16x16x32_bf16(_a7, _bv, accC7, 0,0,0);  \
    _bv = *(const bf16x8*)((Bb) + (BOFF) + 3*2048);                           \
    accD0 = __builtin_amdgcn_mfma_f32_16x16x32_bf16(_a0, _bv, accD0, 0,0,0);  \
    accD1 = __builtin_amdgcn_mfma_f32_16x16x32_bf16(_a1, _bv, accD1, 0,0,0);  \
    accD2 = __builtin_amdgcn_mfma_f32_16x16x32_bf16(_a2, _bv, accD2, 0,0,0);  \
    accD3 = __builtin_amdgcn_mfma_f32_16x16x32_bf16(_a3, _bv, accD3, 0,0,0);  \
    accD4 = __builtin_amdgcn_mfma_f32_16x16x32_bf16(_a4, _bv, accD4, 0,0,0);  \
    accD5 = __builtin_amdgcn_mfma_f32_16x16x32_bf16(_a5, _bv, accD5, 0,0,0);  \
    accD6 = __builtin_amdgcn_mfma_f32_16x16x32_bf16(_a6, _bv, accD6, 0,0,0);  \
    accD7 = __builtin_amdgcn_mfma_f32_16x16x32_bf16(_a7, _bv, accD7, 0,0,0);  \
} while (0)

#define COMPUTE(Ab, Bb) do {                                                  \
    COMPUTE_HALF(Ab, Bb, aK0, bK0);                                           \
    COMPUTE_HALF(Ab, Bb, aK1, bK1);                                           \
} while (0)

#define SYNC do {                                                             \
    asm volatile("s_waitcnt lgkmcnt(0)" ::: "memory");                        \
    __builtin_amdgcn_s_barrier();                                             \
    __builtin_amdgcn_sched_barrier(0);                                        \
} while (0)

// GEMM: grid 256 = 64 nstrips x 4 kq. BN=256 halves A-traffic vs BN=128.
// 512 threads / 8 waves (2M x 4N; wave = 128M x 64N). launch_bounds(512,2)
// -> 256-VGPR cap; acc 128 + prefetch 48 + transients ~36 fits (R12 spilled
// at the 128-cap of a 1024-thread block — that was the regression).
__global__ __launch_bounds__(512, 2)
void gemm_ws(const float* __restrict__ W, const float* __restrict__ bias,
             const unsigned short* __restrict__ wsT,
             float* __restrict__ out, float* __restrict__ wsP)
{
    __shared__ uint4 smem_[(4 * 32768) / 16];  // 128 KiB
    char* const sm = (char*)smem_;
    char* const A0 = sm;                       // A: 256 rows x 128 B
    char* const A1 = sm + 32768;
    char* const B0 = sm + 65536;               // B: 256 rows x 128 B
    char* const B1 = sm + 65536 + 32768;

    const int tid  = threadIdx.x;
    const int lane = tid & 63;
    const int wave = tid >> 6;                 // 0..7
    const int wm = wave >> 2;                  // 0..1 (128 M rows)
    const int wn = wave & 3;                   // 0..3 (64 N cols)
    const int bid    = blockIdx.x;
    const int kq     = bid >> 6;               // 0..3
    const int nstrip = bid & 63;
    const int n0     = nstrip * BN;
    const int kbase  = kq * KQ_LEN;

    // staging geometry: 2 threads per row (rows 0..255)
    const int rr = tid >> 1;                   // row
    const int ph = tid & 1;                    // which half of the 128-B row

    const unsigned short* arow_w = wsT + (size_t)rr * K_TOT + kbase + ph * 32;
    const float* brow = W + (size_t)(n0 + rr) * K_TOT + kbase + ph * 32;

    const int aw0 = swz(rr, 4 * ph + 0);
    const int aw1 = swz(rr, 4 * ph + 1);
    const int aw2 = swz(rr, 4 * ph + 2);
    const int aw3 = swz(rr, 4 * ph + 3);
    const int bw0 = aw0, bw1 = aw1, bw2 = aw2, bw3 = aw3;

    // frag-read bases: XOR invariant under 16-row steps (+2048); kf flips ^64
    const int aK0 = swz(wm * 128 + (lane & 15), lane >> 4);
    const int aK1 = aK0 ^ 64;
    const int bK0 = swz(wn * 64 + (lane & 15), lane >> 4);
    const int bK1 = bK0 ^ 64;

    f32x4 accA0={0,0,0,0},accA1={0,0,0,0},accA2={0,0,0,0},accA3={0,0,0,0};
    f32x4 accA4={0,0,0,0},accA5={0,0,0,0},accA6={0,0,0,0},accA7={0,0,0,0};
    f32x4 accB0={0,0,0,0},accB1={0,0,0,0},accB2={0,0,0,0},accB3={0,0,0,0};
    f32x4 accB4={0,0,0,0},accB5={0,0,0,0},accB6={0,0,0,0},accB7={0,0,0,0};
    f32x4 accC0={0,0,0,0},accC1={0,0,0,0},accC2={0,0,0,0},accC3={0,0,0,0};
    f32x4 accC4={0,0,0,0},accC5={0,0,0,0},accC6={0,0,0,0},accC7={0,0,0,0};
    f32x4 accD0={0,0,0,0},accD1={0,0,0,0},accD2={0,0,0,0},accD3={0,0,0,0};
    f32x4 accD4={0,0,0,0},accD5={0,0,0,0},accD6={0,0,0,0},accD7={0,0,0,0};

    uint4 aR0, aR1, aR2, aR3;
    f32x4 wR0, wR1, wR2, wR3, wR4, wR5, wR6, wR7;

    // prologue
    ISSUE(0);
    STAGE(A0, B0);
    ISSUE(BK);                                 // step-1 loads fly over barrier
    SYNC;

    for (int kt = 0; kt < NQSTEPS; kt += 2) {
        // phase even: compute step kt; stage step kt+1; issue step kt+2
        COMPUTE(A0, B0);
        STAGE(A1, B1);
        if (kt + 2 < NQSTEPS) ISSUE((kt + 2) * BK);
        SYNC;
        // phase odd: compute step kt+1; stage step kt+2; issue step kt+3
        COMPUTE(A1, B1);
        if (kt + 2 < NQSTEPS) STAGE(A0, B0);
        if (kt + 3 < NQSTEPS) ISSUE((kt + 3) * BK);
        SYNC;
    }

    // epilogue: kq==0 writes bias+acc to out; kq>0 writes acc to partial buf.
    float* const dst = (kq == 0) ? out : (wsP + (size_t)(kq - 1) * OUT_ELEMS);
    #pragma unroll
    for (int nf = 0; nf < 4; ++nf) {
        const int col = n0 + wn * 64 + nf * 16 + (lane & 15);
        const float bv = (kq == 0) ? bias[col] : 0.f;
        #pragma unroll
        for (int mf = 0; mf < 8; ++mf) {
            const f32x4 a =
                (nf == 0) ? (mf==0?accA0:mf==1?accA1:mf==2?accA2:mf==3?accA3:
                             mf==4?accA4:mf==5?accA5:mf==6?accA6:accA7) :
                (nf == 1) ? (mf==0?accB0:mf==1?accB1:mf==2?accB2:mf==3?accB3:
                             mf==4?accB4:mf==5?accB5:mf==6?accB6:accB7) :
                (nf == 2) ? (mf==0?accC0:mf==1?accC1:mf==2?accC2:mf==3?accC3:
                             mf==4?accC4:mf==5?accC5:mf==6?accC6:accC7) :
                            (mf==0?accD0:mf==1?accD1:mf==2?accD2:mf==3?accD3:
                             mf==4?accD4:mf==5?accD5:mf==6?accD6:accD7);
            #pragma unroll
            for (int j = 0; j < 4; ++j) {
                int r = wm * 128 + mf * 16 + (lane >> 4) * 4 + j;
                float v = a[j] + bv;
                float* o = (r < 128) ? (dst + (size_t)r * N_TOT + col)
                                     : (dst + HALF_M + (size_t)(r - 128) * N_TOT + col);
                *o = v;
            }
        }
    }
}

extern "C" void kernel_launch(void* const* d_in, const int* in_sizes, int n_in,
                              void* d_out, int out_size, void* d_ws, size_t ws_size,
                              hipStream_t stream) {
    const float* x0 = (const float*)d_in[0];
    const float* x1 = (const float*)d_in[1];
    const float* W  = (const float*)d_in[2];
    const float* b  = (const float*)d_in[3];
    float* out = (float*)d_out;

    const size_t wsT_bytes = (size_t)256 * 16384 * sizeof(unsigned short);  // 8.4 MB

    unsigned short* wsT = (unsigned short*)d_ws;
    float* wsP = (float*)((char*)d_ws + wsT_bytes);

    cvtT_kernel<<<2048, 256, 0, stream>>>(x0, x1, wsT);
    gemm_ws<<<256, 512, 0, stream>>>(W, b, wsT, out, wsP);
    combine_kernel<<<2048, 256, 0, stream>>>(out, wsP, wsP + OUT_ELEMS,
                                             wsP + 2 * OUT_ELEMS);
}